// Round 4
// baseline (1094.643 us; speedup 1.0000x reference)
//
#include <hip/hip_runtime.h>

// Problem constants (B=8, N=4096, n_points=1024, n_samples=32, D_PTS=6, MLPS=[64,64,128])
#define NPTS  4096
#define NB    8
#define NC    1024
#define NSAMP 32
#define DP    6
#define C0    9      // 3 + D_PTS
#define C3    128
#define ROWS_TOT 262144   // NB*NC*NSAMP

// Workspace layout (bytes). Requires ws_size >= ~184 MB.
#define OFF_SS   (32ull<<10)     // 3 layers x {scale[128], shift[128]}
#define OFF_H0   (1ull<<20)      // h0: 262144 x 9 f32 (9.4 MB)
#define OFF_Y0   (16ull<<20)     // y0: 262144 x 64 f32 (67 MB)
#define OFF_Y1   (96ull<<20)     // y1: 262144 x 64 f32 (67 MB)
#define OFF_PSUM (168ull<<20)    // per-block channel sums   [C][NBLK] (max 4 MB)
#define OFF_PSQ  (172ull<<20)    // per-block channel sumsq  [C][NBLK] (max 4 MB)
#define OFF_GMX  (176ull<<20)    // per-centroid channel max [8192][128] (4 MB)
#define OFF_GMN  (180ull<<20)    // per-centroid channel min [8192][128] (4 MB)

typedef unsigned long long ull;

// Exact (no-FMA) squared distance to match numpy rounding; sum order ((x+y)+z).
__device__ __forceinline__ float sqdist_noc(float x, float y, float z,
                                            float cx, float cy, float cz) {
  #pragma clang fp contract(off)
  float dx = x - cx, dy = y - cy, dz = z - cz;
  return dx * dx + dy * dy + dz * dz;
}

// 64-bit DPP move (two 32-bit halves, same ctrl; old=self so masked lanes keep value)
template <int CTRL, int RM>
__device__ __forceinline__ ull dpp_mov_u64(ull x) {
  int lo = (int)(unsigned)(x & 0xFFFFFFFFull);
  int hi = (int)(unsigned)(x >> 32);
  int rlo = __builtin_amdgcn_update_dpp(lo, lo, CTRL, RM, 0xf, false);
  int rhi = __builtin_amdgcn_update_dpp(hi, hi, CTRL, RM, 0xf, false);
  return ((ull)(unsigned)rhi << 32) | (unsigned)rlo;
}

__device__ __forceinline__ ull umax64(ull a, ull b) { return a > b ? a : b; }

// wave64 u64 max reduce, all-VALU (no scalar round-trips); result in lane 63.
__device__ __forceinline__ ull wave64_umax(ull x) {
  x = umax64(x, dpp_mov_u64<0x111, 0xf>(x));  // row_shr:1
  x = umax64(x, dpp_mov_u64<0x112, 0xf>(x));  // row_shr:2
  x = umax64(x, dpp_mov_u64<0x114, 0xf>(x));  // row_shr:4
  x = umax64(x, dpp_mov_u64<0x118, 0xf>(x));  // row_shr:8
  x = umax64(x, dpp_mov_u64<0x142, 0xa>(x));  // row_bcast:15 -> rows 1,3
  x = umax64(x, dpp_mov_u64<0x143, 0xc>(x));  // row_bcast:31 -> rows 2,3
  return x;
}

// ---------------------------------------------------------------------------
// FPS: 1023 sequential farthest-from-last steps. 512 threads, 8 pts/thread.
// Per step: local argmax (8 pts, squared dist) -> pack u64 key
// (sq_bits<<12)|(4095-idx) -> all-VALU DPP u64 max (leader = lane 63) ->
// parity LDS publish -> 1 barrier -> every thread folds 8 keys.
// NO global stores in the loop (avoids vmcnt(0) drain at the barrier);
// selected indices buffered in LDS, centroids emitted once at the end.
// ---------------------------------------------------------------------------
__global__ __launch_bounds__(512)
void fps_kernel(const float* __restrict__ xyz, float* __restrict__ cent) {
  const int b = blockIdx.x;
  const int t = threadIdx.x;
  const float* X = xyz + (size_t)b * NPTS * 3;
  float* OC = cent + (size_t)b * NC * 3;

  __shared__ float4 sxyz[NPTS];                 // 64 KB
  __shared__ alignas(16) ull wk[2][8];
  __shared__ int sidx[NC];                      // 4 KB

  for (int p = t; p < NPTS; p += 512)
    sxyz[p] = make_float4(X[p * 3 + 0], X[p * 3 + 1], X[p * 3 + 2], 0.f);
  __syncthreads();

  float px[8], py[8], pz[8];
  #pragma unroll
  for (int i = 0; i < 8; i++) {
    float4 v = sxyz[t * 8 + i];
    px[i] = v.x; py[i] = v.y; pz[i] = v.z;
  }

  int last = 0;  // deterministic seed index 0
  for (int k = 1; k < NC; k++) {
    const int par = k & 1;
    if (t == 0) sidx[k - 1] = last;             // LDS only; cheap to drain
    float4 c = sxyz[last];                      // broadcast read
    if ((last >> 3) == t) {                     // retire: NaN loses all compares
      int ii = last & 7;
      #pragma unroll
      for (int i = 0; i < 8; i++)
        if (i == ii) px[i] = __int_as_float(0x7FC00000);
    }

    float mx = -1.0f; int mj = 0;
    #pragma unroll
    for (int i = 0; i < 8; i++) {
      float sq = sqdist_noc(px[i], py[i], pz[i], c.x, c.y, c.z);
      if (sq > mx) { mx = sq; mj = i; }         // strict > keeps first index
    }
    // pack: sq >= 0 so bit pattern order == float order; degenerate lane -> 0
    ull key = (mx >= 0.f)
        ? ((ull)(unsigned)__float_as_uint(mx) << 12) |
          (unsigned)(4095 - (t * 8 + mj))       // tie -> smaller idx wins
        : 0ull;
    key = wave64_umax(key);

    if ((t & 63) == 63) wk[par][t >> 6] = key;  // leader = lane 63
    __syncthreads();
    const ulonglong2* W2 = (const ulonglong2*)&wk[par][0];
    ulonglong2 p0 = W2[0], p1 = W2[1], p2 = W2[2], p3 = W2[3];
    ull m0 = umax64(umax64(p0.x, p0.y), umax64(p1.x, p1.y));
    ull m1 = umax64(umax64(p2.x, p2.y), umax64(p3.x, p3.y));
    last = 4095 - (int)(umax64(m0, m1) & 0xFFFull);
  }
  if (t == 0) sidx[NC - 1] = last;
  __syncthreads();
  // one-shot centroid emit
  for (int i = t; i < NC; i += 512) {
    float4 c = sxyz[sidx[i]];
    OC[i * 3 + 0] = c.x;
    OC[i * 3 + 1] = c.y;
    OC[i * 3 + 2] = c.z;
  }
}

// ---------------------------------------------------------------------------
// query_ball + gather + concat, exact stable-argsort semantics via the
// min(dist, r^2=0.04) quirk: points with d >= 0.04 all tie -> stable sort
// emits them in ascending index order. So: compact "inner" points
// (d = sqrt(sq) < 0.04, guard sq < 0.0017), rank-sort them (order-independent
// -> deterministic despite atomics), fill the rest with ascending non-inner
// indices. Centroid itself is always inner (d=0).
// ---------------------------------------------------------------------------
#define BCAP 256
__global__ __launch_bounds__(256)
void ball_kernel(const float* __restrict__ xyz, const float* __restrict__ pts,
                 const float* __restrict__ cent, float* __restrict__ h0) {
  const int blk = blockIdx.x;       // b*NC + c
  const int b = blk >> 10;
  const int t = threadIdx.x;
  const float* X = xyz + (size_t)b * NPTS * 3;
  const float* P = pts + (size_t)b * NPTS * DP;
  const float cx = cent[(size_t)blk * 3 + 0];
  const float cy = cent[(size_t)blk * 3 + 1];
  const float cz = cent[(size_t)blk * 3 + 2];

  __shared__ int scount;
  __shared__ ull skeys[BCAP];
  __shared__ ull ssorted[BCAP];
  __shared__ int sel[NSAMP];
  if (t == 0) scount = 0;
  __syncthreads();

  #pragma unroll
  for (int i = 0; i < 16; i++) {
    int j = t * 16 + i;
    float sq = sqdist_noc(X[j * 3 + 0], X[j * 3 + 1], X[j * 3 + 2], cx, cy, cz);
    if (sq < 0.0017f) {                       // conservative guard
      float d = (sq > 0.f) ? sqrtf(sq) : 0.f; // exact per-reference norm
      if (d < 0.04f) {                        // strictly inside the clip value
        int pos = atomicAdd(&scount, 1);
        if (pos < BCAP)
          skeys[pos] = ((ull)(unsigned)__float_as_int(d) << 12) | (unsigned)j;
      }
    }
  }
  __syncthreads();
  const int M = min(scount, BCAP);

  // rank-sort the inner set (all keys distinct: idx embedded)
  if (t < M) {
    ull my = skeys[t];
    int r = 0;
    for (int j2 = 0; j2 < M; j2++) r += (skeys[j2] < my);
    ssorted[r] = my;
  }
  __syncthreads();

  if (t < NSAMP) {
    int v;
    if (t < M) {
      v = (int)(ssorted[t] & 0xFFFull);
    } else {
      // s-th smallest index NOT in the inner set
      int s = t - M;
      int idx = s;
      for (int it = 0; it < 40; it++) {
        int c = 0;
        for (int j2 = 0; j2 < M; j2++) c += ((int)(skeys[j2] & 0xFFFull) <= idx);
        int nidx = s + c;
        if (nidx == idx) break;
        idx = nidx;
      }
      v = idx;
    }
    sel[t] = v;
  }
  __syncthreads();

  // gather + concat -> h0
  float* H = h0 + (size_t)blk * NSAMP * C0;
  for (int e = t; e < NSAMP * C0; e += 256) {
    int k = e / C0;
    int c = e - k * C0;
    int j = sel[k];
    H[e] = (c < 3) ? X[j * 3 + c] : P[j * DP + (c - 3)];
  }
}

// ---------------------------------------------------------------------------
// dense0: h0[262144,9] @ W[9,64] + b -> y0, with fused deterministic BN
// partials (per-block channel sum/sumsq). 64 rows/block, 4096 blocks.
// ---------------------------------------------------------------------------
__global__ __launch_bounds__(256)
void dense0_kernel(const float* __restrict__ h0, const float* __restrict__ W,
                   const float* __restrict__ bias, float* __restrict__ yout,
                   float* __restrict__ psum, float* __restrict__ psq) {
  __shared__ float xs[64 * C0];
  __shared__ float ws[C0 * 64];
  __shared__ float red[2][16][64];
  const int blk = blockIdx.x, t = threadIdx.x;
  const size_t rbase = (size_t)blk * 64;
  for (int e = t; e < 64 * C0; e += 256) xs[e] = h0[rbase * C0 + e];
  for (int e = t; e < C0 * 64; e += 256) ws[e] = W[e];
  __syncthreads();
  const int rg = t >> 4, cg = t & 15;
  float acc[4][4];
  float4 bv = *(const float4*)(bias + cg * 4);
  #pragma unroll
  for (int r = 0; r < 4; r++) { acc[r][0] = bv.x; acc[r][1] = bv.y; acc[r][2] = bv.z; acc[r][3] = bv.w; }
  #pragma unroll
  for (int k = 0; k < C0; k++) {
    float4 wv = *(const float4*)(ws + k * 64 + cg * 4);
    #pragma unroll
    for (int r = 0; r < 4; r++) {
      float x = xs[(rg * 4 + r) * C0 + k];
      acc[r][0] = fmaf(x, wv.x, acc[r][0]);
      acc[r][1] = fmaf(x, wv.y, acc[r][1]);
      acc[r][2] = fmaf(x, wv.z, acc[r][2]);
      acc[r][3] = fmaf(x, wv.w, acc[r][3]);
    }
  }
  #pragma unroll
  for (int r = 0; r < 4; r++)
    *(float4*)(yout + (rbase + rg * 4 + r) * 64 + cg * 4) =
        make_float4(acc[r][0], acc[r][1], acc[r][2], acc[r][3]);
  #pragma unroll
  for (int c4 = 0; c4 < 4; c4++) {
    float s = 0.f, q = 0.f;
    #pragma unroll
    for (int r = 0; r < 4; r++) { float v = acc[r][c4]; s += v; q = fmaf(v, v, q); }
    red[0][rg][cg * 4 + c4] = s;
    red[1][rg][cg * 4 + c4] = q;
  }
  __syncthreads();
  if (t < 64) {
    float S = 0.f, Q = 0.f;
    #pragma unroll
    for (int g = 0; g < 16; g++) { S += red[0][g][t]; Q += red[1][g][t]; }
    psum[(size_t)t * 4096 + blk] = S;
    psq [(size_t)t * 4096 + blk] = Q;
  }
}

// ---------------------------------------------------------------------------
// dense mid: x = relu(yin*scale+shift) fused on load, y = x @ W[64,COUT] + b,
// fused BN partials; optionally (MM) per-block (=per-centroid) max/min of raw
// y instead of materializing y at all (layer 2).
// ---------------------------------------------------------------------------
template <int RPB, int COUT, int CGN, int NBLKS, bool MM>
__global__ __launch_bounds__(256)
void dense_mid_kernel(const float* __restrict__ yin, const float* __restrict__ ssin,
                      const float* __restrict__ W, const float* __restrict__ bias,
                      float* __restrict__ yout,
                      float* __restrict__ psum, float* __restrict__ psq,
                      float* __restrict__ gmax, float* __restrict__ gmin) {
  constexpr int NG = 256 / CGN;
  __shared__ float xs[RPB * 68];
  __shared__ float ws[64 * COUT];
  __shared__ float scs[64], shs[64];
  __shared__ float red[2][NG][COUT];
  __shared__ float redm[MM ? 2 : 1][MM ? NG : 1][MM ? COUT : 1];
  const int blk = blockIdx.x, t = threadIdx.x;
  if (t < 64) { scs[t] = ssin[t]; shs[t] = ssin[128 + t]; }
  __syncthreads();
  const size_t rbase = (size_t)blk * RPB;
  for (int e = t; e < RPB * 64; e += 256) {
    int c = e & 63;
    float v = yin[rbase * 64 + e];
    xs[(e >> 6) * 68 + c] = fmaxf(fmaf(v, scs[c], shs[c]), 0.f);
  }
  for (int e = t; e < 64 * COUT; e += 256) ws[e] = W[e];
  __syncthreads();
  const int rg = t / CGN, cg = t % CGN;
  float acc[4][4];
  float4 bv = *(const float4*)(bias + cg * 4);
  #pragma unroll
  for (int r = 0; r < 4; r++) { acc[r][0] = bv.x; acc[r][1] = bv.y; acc[r][2] = bv.z; acc[r][3] = bv.w; }
  for (int k0 = 0; k0 < 64; k0 += 4) {
    float4 xv[4];
    #pragma unroll
    for (int r = 0; r < 4; r++)
      xv[r] = *(const float4*)(xs + (rg * 4 + r) * 68 + k0);
    #pragma unroll
    for (int kk = 0; kk < 4; kk++) {
      float4 wv = *(const float4*)(ws + (k0 + kk) * COUT + cg * 4);
      #pragma unroll
      for (int r = 0; r < 4; r++) {
        float x = (&xv[r].x)[kk];
        acc[r][0] = fmaf(x, wv.x, acc[r][0]);
        acc[r][1] = fmaf(x, wv.y, acc[r][1]);
        acc[r][2] = fmaf(x, wv.z, acc[r][2]);
        acc[r][3] = fmaf(x, wv.w, acc[r][3]);
      }
    }
  }
  if constexpr (!MM) {
    #pragma unroll
    for (int r = 0; r < 4; r++)
      *(float4*)(yout + (rbase + rg * 4 + r) * COUT + cg * 4) =
          make_float4(acc[r][0], acc[r][1], acc[r][2], acc[r][3]);
  }
  #pragma unroll
  for (int c4 = 0; c4 < 4; c4++) {
    float s = 0.f, q = 0.f;
    #pragma unroll
    for (int r = 0; r < 4; r++) { float v = acc[r][c4]; s += v; q = fmaf(v, v, q); }
    red[0][rg][cg * 4 + c4] = s;
    red[1][rg][cg * 4 + c4] = q;
    if constexpr (MM) {
      float mx = acc[0][c4], mn = acc[0][c4];
      #pragma unroll
      for (int r = 1; r < 4; r++) { mx = fmaxf(mx, acc[r][c4]); mn = fminf(mn, acc[r][c4]); }
      redm[0][rg][cg * 4 + c4] = mx;
      redm[1][rg][cg * 4 + c4] = mn;
    }
  }
  __syncthreads();
  if (t < COUT) {
    float S = 0.f, Q = 0.f;
    #pragma unroll
    for (int g = 0; g < NG; g++) { S += red[0][g][t]; Q += red[1][g][t]; }
    psum[(size_t)t * NBLKS + blk] = S;
    psq [(size_t)t * NBLKS + blk] = Q;
    if constexpr (MM) {
      float mx = redm[0][0][t], mn = redm[1][0][t];
      #pragma unroll
      for (int g = 1; g < NG; g++) { mx = fmaxf(mx, redm[0][g][t]); mn = fminf(mn, redm[1][g][t]); }
      gmax[(size_t)blk * COUT + t] = mx;
      gmin[(size_t)blk * COUT + t] = mn;
    }
  }
}

// ---------------------------------------------------------------------------
// stats finalize: per channel, fold NBLK partials -> scale/shift.
// ---------------------------------------------------------------------------
template <int NBLK>
__global__ __launch_bounds__(256)
void stats_final_kernel(const float* __restrict__ psum, const float* __restrict__ psq,
                        const float* __restrict__ g, const float* __restrict__ be,
                        float* __restrict__ ss_out) {
  const int c = blockIdx.x, t = threadIdx.x;
  float S = 0.f, Q = 0.f;
  for (int i = t; i < NBLK; i += 256) {
    S += psum[(size_t)c * NBLK + i];
    Q += psq [(size_t)c * NBLK + i];
  }
  __shared__ float sS[256], sQ[256];
  sS[t] = S; sQ[t] = Q;
  __syncthreads();
  #pragma unroll
  for (int off = 128; off; off >>= 1) {
    if (t < off) { sS[t] += sS[t + off]; sQ[t] += sQ[t + off]; }
    __syncthreads();
  }
  if (t == 0) {
    const float inv = 1.0f / 262144.0f;
    float mean = sS[0] * inv;
    float var = sQ[0] * inv - mean * mean;
    float scale = g[c] / sqrtf(var + 1e-3f);
    ss_out[c] = scale;
    ss_out[128 + c] = be[c] - mean * scale;
  }
}

// pool finalize: out1[cent][ch] = relu(sc*(sc>=0?max:min)+sh)
__global__ __launch_bounds__(128)
void pool_final_kernel(const float* __restrict__ gmax, const float* __restrict__ gmin,
                       const float* __restrict__ ss2, float* __restrict__ out1) {
  const int blk = blockIdx.x, c = threadIdx.x;
  const float sc = ss2[c], sh = ss2[128 + c];
  float v = (sc >= 0.f) ? gmax[(size_t)blk * C3 + c] : gmin[(size_t)blk * C3 + c];
  out1[(size_t)blk * C3 + c] = fmaxf(fmaf(v, sc, sh), 0.f);
}

extern "C" void kernel_launch(void* const* d_in, const int* in_sizes, int n_in,
                              void* d_out, int out_size, void* d_ws, size_t ws_size,
                              hipStream_t stream) {
  const float* xyz = (const float*)d_in[0];
  const float* pts = (const float*)d_in[1];
  const float* w0 = (const float*)d_in[2];
  const float* b0 = (const float*)d_in[3];
  const float* g0 = (const float*)d_in[4];
  const float* be0 = (const float*)d_in[5];
  const float* w1 = (const float*)d_in[6];
  const float* b1 = (const float*)d_in[7];
  const float* g1 = (const float*)d_in[8];
  const float* be1 = (const float*)d_in[9];
  const float* w2 = (const float*)d_in[10];
  const float* b2 = (const float*)d_in[11];
  const float* g2 = (const float*)d_in[12];
  const float* be2 = (const float*)d_in[13];

  float* out = (float*)d_out;
  float* cent = out;                       // [8,1024,3]
  float* out1 = out + (size_t)NB * NC * 3; // [8,1024,128]

  char* ws = (char*)d_ws;
  float* ssA  = (float*)(ws + OFF_SS);
  float* h0   = (float*)(ws + OFF_H0);
  float* y0   = (float*)(ws + OFF_Y0);
  float* y1   = (float*)(ws + OFF_Y1);
  float* psum = (float*)(ws + OFF_PSUM);
  float* psq  = (float*)(ws + OFF_PSQ);
  float* gmx  = (float*)(ws + OFF_GMX);
  float* gmn  = (float*)(ws + OFF_GMN);

  fps_kernel<<<dim3(NB), dim3(512), 0, stream>>>(xyz, cent);
  ball_kernel<<<dim3(NB * NC), dim3(256), 0, stream>>>(xyz, pts, cent, h0);

  dense0_kernel<<<dim3(ROWS_TOT / 64), dim3(256), 0, stream>>>(h0, w0, b0, y0, psum, psq);
  stats_final_kernel<4096><<<dim3(64), dim3(256), 0, stream>>>(psum, psq, g0, be0, ssA + 0 * 256);

  dense_mid_kernel<64, 64, 16, 4096, false><<<dim3(ROWS_TOT / 64), dim3(256), 0, stream>>>(
      y0, ssA + 0 * 256, w1, b1, y1, psum, psq, nullptr, nullptr);
  stats_final_kernel<4096><<<dim3(64), dim3(256), 0, stream>>>(psum, psq, g1, be1, ssA + 1 * 256);

  dense_mid_kernel<32, 128, 32, 8192, true><<<dim3(ROWS_TOT / 32), dim3(256), 0, stream>>>(
      y1, ssA + 1 * 256, w2, b2, nullptr, psum, psq, gmx, gmn);
  stats_final_kernel<8192><<<dim3(128), dim3(256), 0, stream>>>(psum, psq, g2, be2, ssA + 2 * 256);

  pool_final_kernel<<<dim3(NB * NC), dim3(128), 0, stream>>>(gmx, gmn, ssA + 2 * 256, out1);

  (void)in_sizes; (void)n_in; (void)out_size; (void)ws_size;
}